// Round 12
// baseline (227.435 us; speedup 1.0000x reference)
//
#include <hip/hip_runtime.h>
#include <math.h>

#define V 100000
#define D 256
#define B 32
#define N 128
#define K 100
#define NPOS (B * N)             // 4096
#define NPAIR (NPOS * (K + 1))   // 413,696 = 404 * 1024 exactly
#define BIN_ROWS 32
#define NBIN (V / BIN_ROWS)      // 3125
#define NSBLK 404                // histogram/placement blocks
#define PPB 1024                 // pairs per block (4 per thread)
#define MAXTOT 512               // plist capacity (bin mean 132, max ~200)
#define BPB 3                    // bins per compute block (cross-bin pipeline)
#define NBLK ((NBIN + BPB - 1) / BPB)  // 1042
#define ROW_W32 136              // u32 words per slab row: 128 + 8 pad
#define HVEC (NPOS * D / 4)      // 262,144 f32x4 groups of hidden
#define NORM_TERM 11.512925f
#define LOG_K 4.605170186f       // log(100)

typedef float    f32x4 __attribute__((ext_vector_type(4)));
typedef unsigned u32x2 __attribute__((ext_vector_type(2)));
typedef unsigned u32x4 __attribute__((ext_vector_type(4)));
typedef __fp16   f16x2 __attribute__((ext_vector_type(2)));

__device__ __forceinline__ float softplus(float x) {
    return fmaxf(x, 0.f) + __logf(1.f + __expf(-fabsf(x)));
}

__device__ __forceinline__ unsigned pack_f16(float a, float b) {
#if __has_builtin(__builtin_amdgcn_cvt_pkrtz)
    f16x2 h = __builtin_amdgcn_cvt_pkrtz(a, b);
#else
    f16x2 h; h.x = (__fp16)a; h.y = (__fp16)b;
#endif
    union { f16x2 h; unsigned u; } c; c.h = h;
    return c.u;
}

#if __has_builtin(__builtin_amdgcn_fdot2)
#define DOT2(a, b, c) __builtin_amdgcn_fdot2((a), (b), (c), false)
#else
__device__ __forceinline__ float DOT2(f16x2 a, f16x2 b, float c) {
    return fmaf((float)a.x, (float)b.x, fmaf((float)a.y, (float)b.y, c));
}
#endif

union V4H { u32x4 u; f16x2 h[4]; };

// Pure-VALU 16-lane butterfly sum via DPP involutions (validated R7-R11).
template <int CTRL>
__device__ __forceinline__ float dpp_add(float x) {
    int y = __builtin_amdgcn_update_dpp(__float_as_int(x), __float_as_int(x),
                                        CTRL, 0xF, 0xF, false);
    return x + __int_as_float(y);
}
__device__ __forceinline__ float quarter_sum(float x) {
    x = dpp_add<0xB1>(x);    // quad_perm [1,0,3,2]
    x = dpp_add<0x4E>(x);    // quad_perm [2,3,0,1]
    x = dpp_add<0x141>(x);   // row_half_mirror
    x = dpp_add<0x140>(x);   // row_mirror
    return x;
}

// decode pair p -> (row, pos, flag)
__device__ __forceinline__ void decode_pair(
    int p, const int* __restrict__ target, const int* __restrict__ noise,
    int& row, int& pos, unsigned& flag)
{
    if (p < NPOS * K) { pos = p / K; row = noise[p]; flag = 0u; }
    else              { pos = p - NPOS * K; row = target[pos]; flag = 1u; }
}

// ---------- H: per-block LDS histogram + fused hidden f32->f16 ----------
__global__ __launch_bounds__(256) void hist_hconv_kernel(
    const int* __restrict__ target, const int* __restrict__ noise,
    const float* __restrict__ hidden,
    unsigned* __restrict__ cnt /* [NSBLK][NBIN] */,
    unsigned* __restrict__ htab32)
{
    __shared__ unsigned hist[NBIN];          // 12.5 KB
    const int blk = blockIdx.x, tid = threadIdx.x;
    for (int i = tid; i < NBIN; i += 256) hist[i] = 0u;
    __syncthreads();
    #pragma unroll
    for (int i = 0; i < 4; ++i) {
        const int p = blk * PPB + i * 256 + tid;   // exact: NPAIR = NSBLK*PPB
        int row, pos; unsigned flag;
        decode_pair(p, target, noise, row, pos, flag);
        atomicAdd(&hist[row >> 5], 1u);            // LDS atomic
    }
    __syncthreads();
    for (int i = tid; i < NBIN; i += 256)          // coalesced count write
        cnt[(size_t)blk * NBIN + i] = hist[i];

    // fused hidden conversion (4 MB read, 2 MB write)
    for (int i = blk * 256 + tid; i < HVEC; i += NSBLK * 256) {
        const f32x4 h4 = *((const f32x4*)hidden + i);
        u32x2 o;
        o.x = pack_f16(h4.x, h4.y);
        o.y = pack_f16(h4.z, h4.w);
        *(u32x2*)(htab32 + (size_t)i * 2) = o;
    }
}

// ---------- S1: per-bin exclusive scan across the 404 block counts ----------
// One wave per bin; cnt[blk][bin] -> exclusive offset in-place; total[bin] out.
__global__ __launch_bounds__(256) void scan_blocks_kernel(
    unsigned* __restrict__ cnt, unsigned* __restrict__ total)
{
    const int wave = threadIdx.x >> 6, lane = threadIdx.x & 63;
    const int bin = blockIdx.x * 4 + wave;
    if (bin >= NBIN) return;
    unsigned carry = 0u;
    #pragma unroll
    for (int i = 0; i < (NSBLK + 63) / 64; ++i) {  // 7 iters
        const int blk = i * 64 + lane;
        unsigned x = (blk < NSBLK) ? cnt[(size_t)blk * NBIN + bin] : 0u;
        unsigned incl = x;
        #pragma unroll
        for (int off = 1; off < 64; off <<= 1) {
            unsigned y = __shfl_up(incl, off, 64);
            if (lane >= off) incl += y;
        }
        if (blk < NSBLK) cnt[(size_t)blk * NBIN + bin] = incl - x + carry;
        carry += __shfl(incl, 63, 64);
    }
    if (lane == 0) total[bin] = carry;
}

// ---------- S2: exclusive scan of 3125 bin totals -> binbase[0..3125] ----------
__global__ __launch_bounds__(256) void scan_bins_kernel(
    const unsigned* __restrict__ total, unsigned* __restrict__ binbase)
{
    __shared__ unsigned wsums[4];
    __shared__ unsigned carry_s;
    const int tid = threadIdx.x, wave = tid >> 6, lane = tid & 63;
    if (tid == 0) carry_s = 0u;
    __syncthreads();
    for (int it = 0; it < (NBIN + 256) / 256 + 1; ++it) {   // covers 0..3125
        const int idx = it * 256 + tid;
        unsigned x = (idx < NBIN) ? total[idx] : 0u;
        unsigned incl = x;
        #pragma unroll
        for (int off = 1; off < 64; off <<= 1) {
            unsigned y = __shfl_up(incl, off, 64);
            if (lane >= off) incl += y;
        }
        if (lane == 63) wsums[wave] = incl;
        __syncthreads();
        unsigned woff = carry_s;
        for (int w = 0; w < wave; ++w) woff += wsums[w];
        if (idx <= NBIN) binbase[idx] = incl - x + woff;
        __syncthreads();
        if (tid == 0) carry_s += wsums[0] + wsums[1] + wsums[2] + wsums[3];
        __syncthreads();
    }
}

// ---------- P: placement — LDS running cursors, zero global atomics ----------
__global__ __launch_bounds__(256) void place_kernel(
    const int* __restrict__ target, const int* __restrict__ noise,
    const unsigned* __restrict__ cnt, const unsigned* __restrict__ binbase,
    unsigned* __restrict__ buf)
{
    __shared__ unsigned run[NBIN];           // 12.5 KB
    const int blk = blockIdx.x, tid = threadIdx.x;
    for (int i = tid; i < NBIN; i += 256)    // global slot base for this block
        run[i] = binbase[i] + cnt[(size_t)blk * NBIN + i];
    __syncthreads();
    #pragma unroll
    for (int i = 0; i < 4; ++i) {
        const int p = blk * PPB + i * 256 + tid;
        int row, pos; unsigned flag;
        decode_pair(p, target, noise, row, pos, flag);
        const unsigned slot = atomicAdd(&run[row >> 5], 1u);   // LDS atomic
        buf[slot] = ((unsigned)(row & (BIN_ROWS - 1)) << 13)
                  | ((unsigned)pos << 1) | flag;
    }
}

// ---------- Compute: BPB bins per block, cross-bin register pipeline ----------
// buf is now bin-contiguous: plist loads are coalesced range copies.
__global__ __launch_bounds__(256, 6) void compute_kernel(
    const unsigned* __restrict__ htab32, const float* __restrict__ weight,
    const float* __restrict__ bias, const float* __restrict__ noise_probs,
    const unsigned* __restrict__ binbase, const unsigned* __restrict__ buf,
    float* __restrict__ out)
{
    __shared__ unsigned slab32[BIN_ROWS * ROW_W32];  // 17.4 KB f16 slab
    __shared__ float    sbias[BPB * BIN_ROWS];
    __shared__ float    slogp[BPB * BIN_ROWS];
    __shared__ unsigned plist[MAXTOT];
    __shared__ unsigned sbase[BPB + 1];
    __shared__ float    wsum[4];

    const int b0  = blockIdx.x * BPB;
    const int tid = threadIdx.x;
    const int wave = tid >> 6;
    const int lane = tid & 63;
    const int q    = lane >> 4;
    const int ql   = lane & 15;

    if (tid <= BPB) sbase[tid] = binbase[min(b0 + tid, NBIN)];
    __syncthreads();

    // stage bin 0 slab, bias/logp for all bins, bin 0 plist
    for (int r = wave; r < BIN_ROWS; r += 4) {
        const f32x4 w4 = __builtin_nontemporal_load(
            (const f32x4*)(weight + (size_t)(b0 * BIN_ROWS + r) * D + lane * 4));
        u32x2 o;
        o.x = pack_f16(w4.x, w4.y);
        o.y = pack_f16(w4.z, w4.w);
        *(u32x2*)(slab32 + r * ROW_W32 + lane * 2) = o;
    }
    if (tid < BPB * BIN_ROWS) {
        const int j = tid >> 5, r = tid & 31, bin = b0 + j;
        if (bin < NBIN) {
            sbias[tid] = bias[bin * BIN_ROWS + r];
            slogp[tid] = __logf(noise_probs[bin * BIN_ROWS + r]);
        }
    }
    {
        const int start0 = sbase[0];
        const int total0 = min((int)(sbase[1] - sbase[0]), MAXTOT);
        for (int i = tid; i < total0; i += 256)     // coalesced
            plist[i] = buf[start0 + i];
    }
    __syncthreads();

    float loss = 0.f;
    for (int j = 0; j < BPB; ++j) {
        const int bin   = b0 + j;
        const int total = min((int)(sbase[j + 1] - sbase[j]), MAXTOT);
        const bool hasnext = (j + 1 < BPB) && (bin + 1 < NBIN);

        // issue next bin's slab loads into registers (in flight below)
        f32x4 wpre[8];
        if (hasnext) {
            const float* wsrc = weight + (size_t)(bin + 1) * BIN_ROWS * D;
            #pragma unroll
            for (int i = 0; i < 8; ++i)
                wpre[i] = __builtin_nontemporal_load(
                    (const f32x4*)(wsrc + (size_t)(wave + 4 * i) * D + lane * 4));
        }
        // prefetch next bin's plist records (coalesced)
        unsigned pl_a = 0u, pl_b = 0u; int tot_n = 0;
        if (hasnext) {
            const int start_n = sbase[j + 1];
            tot_n = min((int)(sbase[j + 2] - sbase[j + 1]), MAXTOT);
            if (tid < tot_n)       pl_a = buf[start_n + tid];
            if (tid + 256 < tot_n) pl_b = buf[start_n + tid + 256];
        }

        // pair loop for bin j (16 lanes/pair, f16 dot2)
        for (int base = wave * 4; base < total; base += 16) {
            const int p = base + q;
            const bool valid = (p < total);
            const unsigned rec = valid ? plist[p] : 0u;
            const int rloc = (int)((rec >> 13) & (BIN_ROWS - 1));
            const int pos  = (int)((rec >> 1) & (NPOS - 1));

            const u32x4* hp = (const u32x4*)(htab32 + (size_t)pos * 128) + ql;
            V4H H0, H1, W0, W1;
            H0.u = hp[0];
            H1.u = hp[16];
            const unsigned* wr = slab32 + rloc * ROW_W32;
            W0.u = *(const u32x4*)(wr + ql * 4);
            W1.u = *(const u32x4*)(wr + 64 + ql * 4);

            float a0 = 0.f, a1 = 0.f, a2 = 0.f, a3 = 0.f;
            a0 = DOT2(H0.h[0], W0.h[0], a0);
            a1 = DOT2(H0.h[1], W0.h[1], a1);
            a2 = DOT2(H0.h[2], W0.h[2], a2);
            a3 = DOT2(H0.h[3], W0.h[3], a3);
            a0 = DOT2(H1.h[0], W1.h[0], a0);
            a1 = DOT2(H1.h[1], W1.h[1], a1);
            a2 = DOT2(H1.h[2], W1.h[2], a2);
            a3 = DOT2(H1.h[3], W1.h[3], a3);

            const float r = quarter_sum((a0 + a1) + (a2 + a3));

            const float score = r + sbias[j * BIN_ROWS + rloc] - NORM_TERM;
            const float x = (rec & 1u) ? (LOG_K - score)
                                       : (score - slogp[j * BIN_ROWS + rloc] - LOG_K);
            if (valid && ql == 0) loss += softplus(x);
        }
        __syncthreads();   // all waves done reading slab/plist of bin j

        if (hasnext) {     // commit prefetched slab + plist for bin j+1
            #pragma unroll
            for (int i = 0; i < 8; ++i) {
                u32x2 o;
                o.x = pack_f16(wpre[i].x, wpre[i].y);
                o.y = pack_f16(wpre[i].z, wpre[i].w);
                *(u32x2*)(slab32 + (wave + 4 * i) * ROW_W32 + lane * 2) = o;
            }
            if (tid < tot_n)       plist[tid]       = pl_a;
            if (tid + 256 < tot_n) plist[tid + 256] = pl_b;
        }
        __syncthreads();
    }

    loss += __shfl_xor(loss, 16, 64);
    loss += __shfl_xor(loss, 32, 64);
    if (lane == 0) wsum[wave] = loss;
    __syncthreads();
    if (tid == 0)
        atomicAdd(out, (wsum[0] + wsum[1] + wsum[2] + wsum[3])
                       * (1.0f / (float)NPOS));
}

extern "C" void kernel_launch(void* const* d_in, const int* in_sizes, int n_in,
                              void* d_out, int out_size, void* d_ws, size_t ws_size,
                              hipStream_t stream) {
    const int*   target      = (const int*)d_in[0];
    const int*   noise       = (const int*)d_in[1];
    const float* hidden      = (const float*)d_in[2];
    const float* weight      = (const float*)d_in[3];
    const float* bias        = (const float*)d_in[4];
    const float* noise_probs = (const float*)d_in[5];
    float* out = (float*)d_out;

    // workspace: cnt (5.05 MB) | total | binbase | buf (1.65 MB) | htab (2 MB)
    char* ws = (char*)d_ws;
    unsigned* cnt     = (unsigned*)ws;                         ws += ((size_t)NSBLK * NBIN * 4 + 255) & ~255ull;
    unsigned* total   = (unsigned*)ws;                         ws += ((size_t)NBIN * 4 + 255) & ~255ull;
    unsigned* binbase = (unsigned*)ws;                         ws += ((size_t)(NBIN + 1) * 4 + 255) & ~255ull;
    unsigned* buf     = (unsigned*)ws;                         ws += ((size_t)NPAIR * 4 + 255) & ~255ull;
    unsigned* htab32  = (unsigned*)ws;

    (void)hipMemsetAsync(out, 0, sizeof(float), stream);   // d_out poisoned 0xAA

    hist_hconv_kernel<<<NSBLK, 256, 0, stream>>>(
        target, noise, hidden, cnt, htab32);
    scan_blocks_kernel<<<(NBIN + 3) / 4, 256, 0, stream>>>(cnt, total);
    scan_bins_kernel<<<1, 256, 0, stream>>>(total, binbase);
    place_kernel<<<NSBLK, 256, 0, stream>>>(target, noise, cnt, binbase, buf);
    compute_kernel<<<NBLK, 256, 0, stream>>>(
        htab32, weight, bias, noise_probs, binbase, buf, out);
}

// Round 13
// 205.154 us; speedup vs baseline: 1.1086x; 1.1086x over previous
//
#include <hip/hip_runtime.h>
#include <math.h>

#define V 100000
#define D 256
#define B 32
#define N 128
#define K 100
#define NPOS (B * N)             // 4096
#define NPAIR (NPOS * (K + 1))   // 413,696 = 1616 * 256 exactly
#define BIN_ROWS 32
#define NBIN (V / BIN_ROWS)      // 3125
#define NSHARD 16
#define CAP_S 32                 // pairs per (bin,shard); mean 8.3, +8 sigma
#define MAXTOT (NSHARD * CAP_S)  // 512
#define BPB 3                    // bins per compute block (cross-bin pipeline)
#define NBLK ((NBIN + BPB - 1) / BPB)  // 1042
#define ROW_W32 136              // u32 words per slab row: 128 + 8 pad
#define HVEC (NPOS * D / 4)      // 262,144 f32x4 groups of hidden to convert
#define NORM_TERM 11.512925f
#define LOG_K 4.605170186f       // log(100)

typedef float    f32x4 __attribute__((ext_vector_type(4)));
typedef unsigned u32x2 __attribute__((ext_vector_type(2)));
typedef unsigned u32x4 __attribute__((ext_vector_type(4)));
typedef __fp16   f16x2 __attribute__((ext_vector_type(2)));

__device__ __forceinline__ float softplus(float x) {
    return fmaxf(x, 0.f) + __logf(1.f + __expf(-fabsf(x)));
}

__device__ __forceinline__ unsigned pack_f16(float a, float b) {
#if __has_builtin(__builtin_amdgcn_cvt_pkrtz)
    f16x2 h = __builtin_amdgcn_cvt_pkrtz(a, b);
#else
    f16x2 h; h.x = (__fp16)a; h.y = (__fp16)b;
#endif
    union { f16x2 h; unsigned u; } c; c.h = h;
    return c.u;
}

#if __has_builtin(__builtin_amdgcn_fdot2)
#define DOT2(a, b, c) __builtin_amdgcn_fdot2((a), (b), (c), false)
#else
__device__ __forceinline__ float DOT2(f16x2 a, f16x2 b, float c) {
    return fmaf((float)a.x, (float)b.x, fmaf((float)a.y, (float)b.y, c));
}
#endif

union V4H { u32x4 u; f16x2 h[4]; };

// Pure-VALU 16-lane butterfly sum via DPP involutions (validated R7-R12).
template <int CTRL>
__device__ __forceinline__ float dpp_add(float x) {
    int y = __builtin_amdgcn_update_dpp(__float_as_int(x), __float_as_int(x),
                                        CTRL, 0xF, 0xF, false);
    return x + __int_as_float(y);
}
__device__ __forceinline__ float quarter_sum(float x) {
    x = dpp_add<0xB1>(x);    // quad_perm [1,0,3,2]
    x = dpp_add<0x4E>(x);    // quad_perm [2,3,0,1]
    x = dpp_add<0x141>(x);   // row_half_mirror
    x = dpp_add<0x140>(x);   // row_mirror
    return x;
}

// ---------- Pass 1: bin pairs (16-way sharded cursors) + hidden f32->f16 ----
// rec = (row%32)<<13 | pos<<1 | is_target
__global__ __launch_bounds__(256) void scatter_hconv_kernel(
    const int* __restrict__ target, const int* __restrict__ noise,
    const float* __restrict__ hidden,
    int* __restrict__ cursor, unsigned* __restrict__ buf,
    unsigned* __restrict__ htab32)
{
    const int p = blockIdx.x * 256 + threadIdx.x;   // grid exact

    int row, pos; unsigned flag;
    if (p < NPOS * K) { pos = p / K; row = noise[p]; flag = 0u; }
    else              { pos = p - NPOS * K; row = target[pos]; flag = 1u; }
    const int cell = (row >> 5) * NSHARD + (blockIdx.x & (NSHARD - 1));
    const int slot = atomicAdd(&cursor[cell], 1);
    if (slot < CAP_S)
        buf[(size_t)cell * CAP_S + slot] =
            ((unsigned)(row & (BIN_ROWS - 1)) << 13) | ((unsigned)pos << 1) | flag;

    if (p < HVEC) {                      // fused hidden f32->f16 (4 MB read)
        const f32x4 h4 = *((const f32x4*)hidden + p);
        u32x2 o;
        o.x = pack_f16(h4.x, h4.y);
        o.y = pack_f16(h4.z, h4.w);
        *(u32x2*)(htab32 + (size_t)p * 2) = o;
    }
}

// ---------- Pass 2: BPB bins per block, cross-bin register pipeline ----------
// Plus 1-deep in-loop hidden prefetch: while pair p computes, pair p+16's
// 512B f16 hidden row is in flight (global L2 latency overlapped).
// launch_bounds(256,4): grid is 4 blocks/CU anyway; VGPR cap 128 keeps the
// compiler from sinking the prefetch (R7's VGPR=36 defeat).
__global__ __launch_bounds__(256, 4) void compute_kernel(
    const unsigned* __restrict__ htab32, const float* __restrict__ weight,
    const float* __restrict__ bias, const float* __restrict__ noise_probs,
    const int* __restrict__ cursor, const unsigned* __restrict__ buf,
    float* __restrict__ out)
{
    __shared__ unsigned slab32[BIN_ROWS * ROW_W32];  // 17.4 KB f16 slab
    __shared__ float    sbias[BPB * BIN_ROWS];
    __shared__ float    slogp[BPB * BIN_ROWS];
    __shared__ unsigned plist[MAXTOT];
    __shared__ int      scnt[BPB * NSHARD];
    __shared__ int      pref[BPB][NSHARD + 1];
    __shared__ float    wsum[4];

    const int b0  = blockIdx.x * BPB;
    const int tid = threadIdx.x;
    const int wave = tid >> 6;
    const int lane = tid & 63;
    const int q    = lane >> 4;
    const int ql   = lane & 15;

    // ---- prologue: cursors + prefixes for all BPB bins
    if (tid < BPB * NSHARD) {
        const int j = tid >> 4, s = tid & 15, bin = b0 + j;
        scnt[tid] = (bin < NBIN) ? min(cursor[bin * NSHARD + s], CAP_S) : 0;
    }
    __syncthreads();
    if (tid < BPB) {
        int s = 0;
        #pragma unroll
        for (int i = 0; i < NSHARD; ++i) { pref[tid][i] = s; s += scnt[tid * NSHARD + i]; }
        pref[tid][NSHARD] = s;
    }
    __syncthreads();

    // ---- stage bin 0 slab + plist, and bias/logp for all bins
    for (int r = wave; r < BIN_ROWS; r += 4) {
        const f32x4 w4 = __builtin_nontemporal_load(
            (const f32x4*)(weight + (size_t)(b0 * BIN_ROWS + r) * D + lane * 4));
        u32x2 o;
        o.x = pack_f16(w4.x, w4.y);
        o.y = pack_f16(w4.z, w4.w);
        *(u32x2*)(slab32 + r * ROW_W32 + lane * 2) = o;
    }
    if (tid < BPB * BIN_ROWS) {
        const int j = tid >> 5, r = tid & 31, bin = b0 + j;
        if (bin < NBIN) {
            sbias[tid] = bias[bin * BIN_ROWS + r];
            slogp[tid] = __logf(noise_probs[bin * BIN_ROWS + r]);
        }
    }
    {
        const int total0 = pref[0][NSHARD];
        for (int i = tid; i < total0; i += 256) {
            int s = 0;
            #pragma unroll
            for (int m = 1; m < NSHARD; ++m) s += (i >= pref[0][m]);
            plist[i] = buf[((size_t)(b0 * NSHARD + s)) * CAP_S + (i - pref[0][s])];
        }
    }
    __syncthreads();

    float loss = 0.f;
    for (int j = 0; j < BPB; ++j) {
        const int bin   = b0 + j;
        const int total = (bin < NBIN) ? pref[j][NSHARD] : 0;
        const bool hasnext = (j + 1 < BPB) && (bin + 1 < NBIN);

        // ---- issue next bin's slab loads into registers (in flight below)
        f32x4 wpre[8];
        if (hasnext) {
            const float* wsrc = weight + (size_t)(bin + 1) * BIN_ROWS * D;
            #pragma unroll
            for (int i = 0; i < 8; ++i)
                wpre[i] = __builtin_nontemporal_load(
                    (const f32x4*)(wsrc + (size_t)(wave + 4 * i) * D + lane * 4));
        }
        // ---- prefetch next bin's plist records into registers
        unsigned pl_a = 0u, pl_b = 0u; int tot_n = 0;
        if (hasnext) {
            tot_n = pref[j + 1][NSHARD];
            if (tid < tot_n) {
                int s = 0;
                #pragma unroll
                for (int m = 1; m < NSHARD; ++m) s += (tid >= pref[j + 1][m]);
                pl_a = buf[((size_t)((bin + 1) * NSHARD + s)) * CAP_S + (tid - pref[j + 1][s])];
            }
            if (tid + 256 < tot_n) {
                int s = 0;
                #pragma unroll
                for (int m = 1; m < NSHARD; ++m) s += (tid + 256 >= pref[j + 1][m]);
                pl_b = buf[((size_t)((bin + 1) * NSHARD + s)) * CAP_S + (tid + 256 - pref[j + 1][s])];
            }
        }

        // ---- pair loop for bin j: 16 lanes/pair, 1-deep hidden prefetch
        {
            const int p0 = wave * 4 + q;
            unsigned rec_c = (p0 < total) ? plist[p0] : 0u;
            V4H H0c, H1c;
            {
                const u32x4* hp = (const u32x4*)(htab32
                    + (size_t)((rec_c >> 1) & (NPOS - 1)) * 128) + ql;
                H0c.u = hp[0];
                H1c.u = hp[16];
            }
            for (int base = wave * 4; base < total; base += 16) {
                const int p = base + q;
                // prefetch pair p+16's record + hidden row (in flight during dots)
                const int pn = p + 16;
                const unsigned rec_n = (pn < total) ? plist[pn] : 0u;
                const u32x4* hpn = (const u32x4*)(htab32
                    + (size_t)((rec_n >> 1) & (NPOS - 1)) * 128) + ql;
                V4H H0n, H1n;
                H0n.u = hpn[0];
                H1n.u = hpn[16];

                // compute pair p with pipelined hidden (H0c/H1c), slab at use
                const int rloc = (int)((rec_c >> 13) & (BIN_ROWS - 1));
                const unsigned* wr = slab32 + rloc * ROW_W32;
                V4H W0, W1;
                W0.u = *(const u32x4*)(wr + ql * 4);
                W1.u = *(const u32x4*)(wr + 64 + ql * 4);

                float a0 = 0.f, a1 = 0.f, a2 = 0.f, a3 = 0.f;
                a0 = DOT2(H0c.h[0], W0.h[0], a0);
                a1 = DOT2(H0c.h[1], W0.h[1], a1);
                a2 = DOT2(H0c.h[2], W0.h[2], a2);
                a3 = DOT2(H0c.h[3], W0.h[3], a3);
                a0 = DOT2(H1c.h[0], W1.h[0], a0);
                a1 = DOT2(H1c.h[1], W1.h[1], a1);
                a2 = DOT2(H1c.h[2], W1.h[2], a2);
                a3 = DOT2(H1c.h[3], W1.h[3], a3);

                const float r = quarter_sum((a0 + a1) + (a2 + a3));

                const float score = r + sbias[j * BIN_ROWS + rloc] - NORM_TERM;
                const float x = (rec_c & 1u) ? (LOG_K - score)
                                             : (score - slogp[j * BIN_ROWS + rloc] - LOG_K);
                if ((p < total) && ql == 0) loss += softplus(x);

                rec_c = rec_n;
                H0c = H0n;
                H1c = H1n;
            }
        }
        __syncthreads();   // all waves done reading slab/plist of bin j

        if (hasnext) {     // commit prefetched slab + plist for bin j+1
            #pragma unroll
            for (int i = 0; i < 8; ++i) {
                u32x2 o;
                o.x = pack_f16(wpre[i].x, wpre[i].y);
                o.y = pack_f16(wpre[i].z, wpre[i].w);
                *(u32x2*)(slab32 + (wave + 4 * i) * ROW_W32 + lane * 2) = o;
            }
            if (tid < tot_n)       plist[tid]       = pl_a;
            if (tid + 256 < tot_n) plist[tid + 256] = pl_b;
        }
        __syncthreads();
    }

    // fold quarters (loss lives on ql==0 lanes), then waves
    loss += __shfl_xor(loss, 16, 64);
    loss += __shfl_xor(loss, 32, 64);
    if (lane == 0) wsum[wave] = loss;
    __syncthreads();
    if (tid == 0)
        atomicAdd(out, (wsum[0] + wsum[1] + wsum[2] + wsum[3])
                       * (1.0f / (float)NPOS));
}

extern "C" void kernel_launch(void* const* d_in, const int* in_sizes, int n_in,
                              void* d_out, int out_size, void* d_ws, size_t ws_size,
                              hipStream_t stream) {
    const int*   target      = (const int*)d_in[0];
    const int*   noise       = (const int*)d_in[1];
    const float* hidden      = (const float*)d_in[2];
    const float* weight      = (const float*)d_in[3];
    const float* bias        = (const float*)d_in[4];
    const float* noise_probs = (const float*)d_in[5];
    float* out = (float*)d_out;

    // workspace: cursors (200 KB) | pair records (6.4 MB) | f16 hidden (2 MB)
    const size_t cursor_bytes = (size_t)NBIN * NSHARD * 4;
    const size_t buf_bytes    = (size_t)NBIN * NSHARD * CAP_S * 4;
    int*      cursor = (int*)d_ws;
    unsigned* buf    = (unsigned*)((char*)d_ws + cursor_bytes);
    unsigned* htab32 = (unsigned*)((char*)d_ws + cursor_bytes + buf_bytes);

    (void)hipMemsetAsync(cursor, 0, cursor_bytes, stream);
    (void)hipMemsetAsync(out, 0, sizeof(float), stream);   // d_out poisoned 0xAA

    scatter_hconv_kernel<<<NPAIR / 256, 256, 0, stream>>>(
        target, noise, hidden, cursor, buf, htab32);
    compute_kernel<<<NBLK, 256, 0, stream>>>(
        htab32, weight, bias, noise_probs, cursor, buf, out);
}